// Round 1
// baseline (666.811 us; speedup 1.0000x reference)
//
#include <hip/hip_runtime.h>

// Problem constants (from reference): B=4, S=4096, H=1024, R=16
#define BQ 4
#define SQ 4096
#define HQ 1024
#define RQ 16

// ---------------------------------------------------------------------------
// Kernel 0: besum[h] = sum_r be[r][h]   (1024 outputs, trivial)
// ---------------------------------------------------------------------------
__global__ void besum_kernel(const float* __restrict__ be, float* __restrict__ besum) {
    int h = blockIdx.x * 256 + threadIdx.x;  // grid = 4 blocks x 256
    float s = 0.f;
#pragma unroll
    for (int r = 0; r < RQ; ++r) s += be[r * HQ + h];
    besum[h] = s;
}

// ---------------------------------------------------------------------------
// Kernel 1: per (row, r) thread computes
//   P[row][r] = (hs[row]·wc[r] + bc[r]) * strength[r]
//   U[row][r] =  hs[row]·we[r]
//   V[row]    =  hs[row]·besum          (written by r==0 lanes)
// row = b*S + s, 16384 rows total. Block = 256 threads = 16 rows x 16 rules.
// hs row is shared by 16 adjacent lanes (same-address broadcast in L1);
// wc/we (128 KB total) stay L2-resident.
// ---------------------------------------------------------------------------
__global__ void proj_kernel(const float* __restrict__ hs,
                            const float* __restrict__ wc,
                            const float* __restrict__ bc,
                            const float* __restrict__ we,
                            const float* __restrict__ strength,
                            const float* __restrict__ besum,
                            float* __restrict__ P,
                            float* __restrict__ U,
                            float* __restrict__ V) {
    const int tid = threadIdx.x;
    const int r = tid & 15;
    const int rowLoc = tid >> 4;
    const int row = blockIdx.x * 16 + rowLoc;  // [0, 16384)

    const float4* hs4 = reinterpret_cast<const float4*>(hs + (size_t)row * HQ);
    const float4* wc4 = reinterpret_cast<const float4*>(wc + (size_t)r * HQ);
    const float4* we4 = reinterpret_cast<const float4*>(we + (size_t)r * HQ);
    const float4* bs4 = reinterpret_cast<const float4*>(besum);

    float accC = 0.f, accE = 0.f, accV = 0.f;
#pragma unroll 4
    for (int j = 0; j < HQ / 4; ++j) {
        float4 h4 = hs4[j];
        float4 c4 = wc4[j];
        float4 e4 = we4[j];
        float4 b4 = bs4[j];  // same addr across wave -> broadcast
        accC = fmaf(h4.x, c4.x, fmaf(h4.y, c4.y, fmaf(h4.z, c4.z, fmaf(h4.w, c4.w, accC))));
        accE = fmaf(h4.x, e4.x, fmaf(h4.y, e4.y, fmaf(h4.z, e4.z, fmaf(h4.w, e4.w, accE))));
        accV = fmaf(h4.x, b4.x, fmaf(h4.y, b4.y, fmaf(h4.z, b4.z, fmaf(h4.w, b4.w, accV))));
    }

    P[(size_t)row * RQ + r] = (accC + bc[r]) * strength[r];
    U[(size_t)row * RQ + r] = accE;
    if (r == 0) V[row] = accV;
}

// ---------------------------------------------------------------------------
// Kernel 2: bias[b,s,t] = sum_k P[b,s,k]*U[b,t,k] + v[b,t]
// Block: 256 threads covers a 64(s) x 64(t) tile; thread = 4s x 4t micro-tile.
// Stores: each thread 4x float4, lanes 0..15 cover 64 contiguous t floats.
// ---------------------------------------------------------------------------
__global__ void __launch_bounds__(256)
bias_kernel(const float* __restrict__ P,
            const float* __restrict__ U,
            const float* __restrict__ V,
            float* __restrict__ out) {
    const int b = blockIdx.z;
    const int ts = threadIdx.x & 15;
    const int ss = threadIdx.x >> 4;
    const int t0 = blockIdx.x * 64 + ts * 4;
    const int s0 = blockIdx.y * 64 + ss * 4;

    const float4* P4 = reinterpret_cast<const float4*>(P + ((size_t)b * SQ + s0) * RQ);
    const float4* U4 = reinterpret_cast<const float4*>(U + ((size_t)b * SQ + t0) * RQ);

    float4 p[4][4], u[4][4];
#pragma unroll
    for (int i = 0; i < 4; ++i) {
#pragma unroll
        for (int k = 0; k < 4; ++k) {
            p[i][k] = P4[i * 4 + k];  // P row (s0+i), 16 floats
            u[i][k] = U4[i * 4 + k];  // U row (t0+i), 16 floats
        }
    }
    const float4 v4 = *reinterpret_cast<const float4*>(V + (size_t)b * SQ + t0);

#pragma unroll
    for (int i = 0; i < 4; ++i) {
        float acc[4];
#pragma unroll
        for (int j = 0; j < 4; ++j) {
            float a = 0.f;
#pragma unroll
            for (int k = 0; k < 4; ++k) {
                a = fmaf(p[i][k].x, u[j][k].x, a);
                a = fmaf(p[i][k].y, u[j][k].y, a);
                a = fmaf(p[i][k].z, u[j][k].z, a);
                a = fmaf(p[i][k].w, u[j][k].w, a);
            }
            acc[j] = a;
        }
        float4 o;
        o.x = acc[0] + v4.x;
        o.y = acc[1] + v4.y;
        o.z = acc[2] + v4.z;
        o.w = acc[3] + v4.w;
        *reinterpret_cast<float4*>(out + ((size_t)b * SQ + s0 + i) * SQ + t0) = o;
    }
}

// ---------------------------------------------------------------------------
extern "C" void kernel_launch(void* const* d_in, const int* in_sizes, int n_in,
                              void* d_out, int out_size, void* d_ws, size_t ws_size,
                              hipStream_t stream) {
    const float* hs       = (const float*)d_in[0];  // [B,S,H]
    const float* wc       = (const float*)d_in[1];  // [R,H]
    const float* bc       = (const float*)d_in[2];  // [R]
    const float* we       = (const float*)d_in[3];  // [R,H]
    const float* be       = (const float*)d_in[4];  // [R,H]
    const float* strength = (const float*)d_in[5];  // [R]
    float* out = (float*)d_out;                     // [B,S,S]

    float* ws    = (float*)d_ws;
    float* besum = ws;                       // 1024 floats
    float* P     = besum + HQ;               // B*S*R = 262144 floats
    float* U     = P + (size_t)BQ * SQ * RQ; // 262144 floats
    float* V     = U + (size_t)BQ * SQ * RQ; // 16384 floats
    // total ws use: ~2.1 MB

    besum_kernel<<<dim3(HQ / 256), dim3(256), 0, stream>>>(be, besum);
    proj_kernel<<<dim3((BQ * SQ) / 16), dim3(256), 0, stream>>>(
        hs, wc, bc, we, strength, besum, P, U, V);
    bias_kernel<<<dim3(SQ / 64, SQ / 64, BQ), dim3(256), 0, stream>>>(P, U, V, out);
}

// Round 3
// 525.327 us; speedup vs baseline: 1.2693x; 1.2693x over previous
//
#include <hip/hip_runtime.h>

// Problem constants: B=4, S=4096, H=1024, R=16
#define BQ 4
#define SQ 4096
#define HQ 1024
#define RQ 16
#define NROWS (BQ * SQ)   // 16384
#define KSPLIT 8          // K split into 8 chunks of 128
#define PITCH 36          // cols: 0-15 raw cause-dot, 16-31 U, 32 V, 33-35 pad
#define PITCH4 9
#define HSPITCH 68        // LDS row pitch (multiple of 4 for b128 alignment)

typedef float vfloat4 __attribute__((ext_vector_type(4)));

// ---------------------------------------------------------------------------
// besum[h] = sum_r be[r][h]
// ---------------------------------------------------------------------------
__global__ void besum_kernel(const float* __restrict__ be, float* __restrict__ besum) {
    int h = blockIdx.x * 256 + threadIdx.x;
    float s = 0.f;
#pragma unroll
    for (int r = 0; r < RQ; ++r) s += be[r * HQ + h];
    besum[h] = s;
}

// ---------------------------------------------------------------------------
// proj: GEMM [16384 x 1024] x [1024 x 33] with K-split.
// Block = 512 threads = 8 waves. Wave w owns cols 4w..4w+3 (wave-uniform ->
// weights go through the scalar path). Lane owns rows R0 + lane + 64*i.
// hs tile (256 rows x 64 k) staged coalesced into LDS.
// Output: Pp[ks][row][36] raw dots (affine applied later); wave 0 also
// accumulates V = hs . besum into col 32.
// ---------------------------------------------------------------------------
__global__ void __launch_bounds__(512, 4)
proj_kernel(const float* __restrict__ hs, const float* __restrict__ wc,
            const float* __restrict__ we, const float* __restrict__ besum,
            float* __restrict__ Pp) {
    __shared__ float hs_lds[256 * HSPITCH];  // 69.6 KB -> 2 blocks/CU
    const int tid = threadIdx.x;
    const int lane = tid & 63;
    const int wave = __builtin_amdgcn_readfirstlane(tid >> 6);
    const int R0 = blockIdx.x * 256;
    const int ks = blockIdx.y;
    const int c0 = wave * 4;
    const float* wbase = (c0 < 16) ? (wc + c0 * HQ) : (we + (c0 - 16) * HQ);

    float acc[4][4] = {{0.f}};
    float vacc[4] = {0.f, 0.f, 0.f, 0.f};

    for (int kc = 0; kc < 2; ++kc) {
        const int k0 = ks * 128 + kc * 64;
        // --- stage hs[R0..R0+255][k0..k0+63] into LDS, fully coalesced ---
#pragma unroll
        for (int q = 0; q < 8; ++q) {
            int f = q * 512 + tid;        // float4 index within tile
            int row_l = f >> 4;           // 16 float4 per row
            int kk = (f & 15) << 2;
            float4 v = *(const float4*)(hs + (size_t)(R0 + row_l) * HQ + k0 + kk);
            *(float4*)&hs_lds[row_l * HSPITCH + kk] = v;
        }
        __syncthreads();
#pragma unroll
        for (int j = 0; j < 16; ++j) {
            // wave-uniform weight fragments (scalar loads)
            float4 w0 = *(const float4*)(wbase + 0 * HQ + k0 + 4 * j);
            float4 w1 = *(const float4*)(wbase + 1 * HQ + k0 + 4 * j);
            float4 w2 = *(const float4*)(wbase + 2 * HQ + k0 + 4 * j);
            float4 w3 = *(const float4*)(wbase + 3 * HQ + k0 + 4 * j);
            float4 b4;
            if (wave == 0) b4 = *(const float4*)(besum + k0 + 4 * j);
#pragma unroll
            for (int i = 0; i < 4; ++i) {
                float4 h = *(const float4*)&hs_lds[(lane + 64 * i) * HSPITCH + 4 * j];
                acc[i][0] = fmaf(h.x, w0.x, fmaf(h.y, w0.y, fmaf(h.z, w0.z, fmaf(h.w, w0.w, acc[i][0]))));
                acc[i][1] = fmaf(h.x, w1.x, fmaf(h.y, w1.y, fmaf(h.z, w1.z, fmaf(h.w, w1.w, acc[i][1]))));
                acc[i][2] = fmaf(h.x, w2.x, fmaf(h.y, w2.y, fmaf(h.z, w2.z, fmaf(h.w, w2.w, acc[i][2]))));
                acc[i][3] = fmaf(h.x, w3.x, fmaf(h.y, w3.y, fmaf(h.z, w3.z, fmaf(h.w, w3.w, acc[i][3]))));
                if (wave == 0)
                    vacc[i] = fmaf(h.x, b4.x, fmaf(h.y, b4.y, fmaf(h.z, b4.z, fmaf(h.w, b4.w, vacc[i]))));
            }
        }
        __syncthreads();
    }
#pragma unroll
    for (int i = 0; i < 4; ++i) {
        int row = R0 + lane + 64 * i;
        size_t base = ((size_t)ks * NROWS + row) * PITCH;
        float4 o = make_float4(acc[i][0], acc[i][1], acc[i][2], acc[i][3]);
        *(float4*)(Pp + base + c0) = o;
        if (wave == 0) Pp[base + 32] = vacc[i];
    }
}

// ---------------------------------------------------------------------------
// reduce: PU[row][36] = sum_ks Pp[ks][row][36]; cols 0-15 get (x+bc)*strength
// ---------------------------------------------------------------------------
__global__ void reduce_kernel(const float* __restrict__ Pp, const float* __restrict__ bc,
                              const float* __restrict__ strength, float* __restrict__ PU) {
    int idx = blockIdx.x * 256 + threadIdx.x;  // 16384*9 threads
    int row = idx / 9;
    int c4 = idx - row * 9;
    const float4* Pp4 = (const float4*)Pp;
    float4 s = make_float4(0.f, 0.f, 0.f, 0.f);
#pragma unroll
    for (int ks = 0; ks < KSPLIT; ++ks) {
        float4 t = Pp4[((size_t)ks * NROWS + row) * PITCH4 + c4];
        s.x += t.x; s.y += t.y; s.z += t.z; s.w += t.w;
    }
    if (c4 < 4) {
        int c = c4 * 4;
        s.x = (s.x + bc[c + 0]) * strength[c + 0];
        s.y = (s.y + bc[c + 1]) * strength[c + 1];
        s.z = (s.z + bc[c + 2]) * strength[c + 2];
        s.w = (s.w + bc[c + 3]) * strength[c + 3];
    }
    ((float4*)PU)[(size_t)row * PITCH4 + c4] = s;
}

// ---------------------------------------------------------------------------
// bias[b,s,t] = sum_r P[b,s,r]*U[b,t,r] + V[b,t]
// 64x64 tile / block, 4sx4t per thread; k looped in quads to keep VGPRs low.
// ---------------------------------------------------------------------------
__global__ void __launch_bounds__(256)
bias_kernel(const float* __restrict__ PU, float* __restrict__ out) {
    const int b = blockIdx.z;
    const int ts = threadIdx.x & 15;
    const int ss = threadIdx.x >> 4;
    const int t0 = blockIdx.x * 64 + ts * 4;
    const int s0 = blockIdx.y * 64 + ss * 4;
    const float4* PU4 = (const float4*)PU;
    const size_t rbase = (size_t)b * SQ;

    float acc[4][4] = {{0.f}};
#pragma unroll
    for (int kq = 0; kq < 4; ++kq) {
        float4 p[4], u[4];
#pragma unroll
        for (int i = 0; i < 4; ++i) p[i] = PU4[(rbase + s0 + i) * PITCH4 + kq];
#pragma unroll
        for (int j = 0; j < 4; ++j) u[j] = PU4[(rbase + t0 + j) * PITCH4 + 4 + kq];
#pragma unroll
        for (int i = 0; i < 4; ++i)
#pragma unroll
            for (int j = 0; j < 4; ++j)
                acc[i][j] = fmaf(p[i].x, u[j].x, fmaf(p[i].y, u[j].y,
                            fmaf(p[i].z, u[j].z, fmaf(p[i].w, u[j].w, acc[i][j]))));
    }
    float v[4];
#pragma unroll
    for (int j = 0; j < 4; ++j) v[j] = PU[(rbase + t0 + j) * PITCH + 32];
#pragma unroll
    for (int i = 0; i < 4; ++i) {
        vfloat4 o;
        o.x = acc[i][0] + v[0];
        o.y = acc[i][1] + v[1];
        o.z = acc[i][2] + v[2];
        o.w = acc[i][3] + v[3];
        __builtin_nontemporal_store(o, (vfloat4*)(out + (rbase + s0 + i) * SQ + t0));
    }
}

// ---------------------------------------------------------------------------
extern "C" void kernel_launch(void* const* d_in, const int* in_sizes, int n_in,
                              void* d_out, int out_size, void* d_ws, size_t ws_size,
                              hipStream_t stream) {
    const float* hs       = (const float*)d_in[0];  // [B,S,H]
    const float* wc       = (const float*)d_in[1];  // [R,H]
    const float* bc       = (const float*)d_in[2];  // [R]
    const float* we       = (const float*)d_in[3];  // [R,H]
    const float* be       = (const float*)d_in[4];  // [R,H]
    const float* strength = (const float*)d_in[5];  // [R]
    float* out = (float*)d_out;                     // [B,S,S]

    float* ws    = (float*)d_ws;
    float* besum = ws;                                        // 1024
    float* Pp    = besum + HQ;                                // 8*16384*36 floats
    float* PU    = Pp + (size_t)KSPLIT * NROWS * PITCH;       // 16384*36 floats
    // total ws use ~21.3 MB

    besum_kernel<<<dim3(HQ / 256), dim3(256), 0, stream>>>(be, besum);
    proj_kernel<<<dim3(NROWS / 256, KSPLIT), dim3(512), 0, stream>>>(hs, wc, we, besum, Pp);
    reduce_kernel<<<dim3(NROWS * PITCH4 / 256), dim3(256), 0, stream>>>(Pp, bc, strength, PU);
    bias_kernel<<<dim3(SQ / 64, SQ / 64, BQ), dim3(256), 0, stream>>>(PU, out);
}